// Round 2
// baseline (1220.745 us; speedup 1.0000x reference)
//
#include <hip/hip_runtime.h>
#include <hip/hip_bf16.h>
#include <math.h>

// ---- static problem config ----
// B=24, H=W=60, DIM=256, NH=8, HD=32, WS=7, SS=3, N=49, HP=WP=63, NW=81
// rows_att = 24*81*49 = 95256 ; rows_mlp = 24*3600 = 86400
// Workspace is chunk-adaptive: per-chunk scratch = cb*9404928 B + 1.5 MB weights.

typedef _Float16 half8 __attribute__((ext_vector_type(8)));
typedef float f32x4 __attribute__((ext_vector_type(4)));

__device__ __forceinline__ float wave_reduce_sum(float v) {
  v += __shfl_xor(v, 1);
  v += __shfl_xor(v, 2);
  v += __shfl_xor(v, 4);
  v += __shfl_xor(v, 8);
  v += __shfl_xor(v, 16);
  v += __shfl_xor(v, 32);
  return v;
}

// ---------------- weight transpose + f16 convert (Bt layout: N x K) -----------
__global__ __launch_bounds__(256) void prep_weights(
    const float* __restrict__ wqkv, const float* __restrict__ wproj,
    const float* __restrict__ wfc1, const float* __restrict__ wfc2,
    _Float16* __restrict__ oqkv, _Float16* __restrict__ oproj,
    _Float16* __restrict__ ofc1, _Float16* __restrict__ ofc2)
{
  int idx = blockIdx.x * 256 + threadIdx.x;
  if (idx < 196608) {                       // w_qkv: 256x768 -> 768x256
    int n = idx / 256, k = idx % 256;
    oqkv[idx] = (_Float16)wqkv[k * 768 + n];
  } else if (idx < 262144) {                // w_proj: 256x256 -> 256x256
    int i = idx - 196608; int n = i / 256, k = i % 256;
    oproj[i] = (_Float16)wproj[k * 256 + n];
  } else if (idx < 524288) {                // w_fc1: 256x1024 -> 1024x256
    int i = idx - 262144; int n = i / 256, k = i % 256;
    ofc1[i] = (_Float16)wfc1[k * 1024 + n];
  } else {                                  // w_fc2: 1024x256 -> 256x1024
    int i = idx - 524288; int n = i / 1024, k = i % 1024;
    ofc2[i] = (_Float16)wfc2[k * 256 + n];
  }
}

// --------- LN1 fused with pad + cyclic shift(-3,-3) + window partition --------
// global row r = bw*49+n ; source (sh,sw) = ((wh*7+i+3)%63, (ww*7+j+3)%63); pad->0
__global__ __launch_bounds__(256) void ln1_window_kernel(
    const float* __restrict__ x, const float* __restrict__ g,
    const float* __restrict__ bta, _Float16* __restrict__ xw,
    int row0, int rows_c)
{
  int lrow = blockIdx.x * 4 + (threadIdx.x >> 6);
  if (lrow >= rows_c) return;               // whole wave exits together
  int row = row0 + lrow;
  int lane = threadIdx.x & 63;
  int bw = row / 49, n = row - bw * 49;
  int b = bw / 81, win = bw - b * 81;
  int wh = win / 9, ww = win - wh * 9;
  int i = n / 7, j = n - i * 7;
  int sh = wh * 7 + i + 3; if (sh >= 63) sh -= 63;
  int sw = ww * 7 + j + 3; if (sw >= 63) sw -= 63;
  bool valid = (sh < 60) && (sw < 60);
  float4 v = make_float4(0.f, 0.f, 0.f, 0.f);
  if (valid)
    v = reinterpret_cast<const float4*>(x + ((size_t)b * 3600 + sh * 60 + sw) * 256)[lane];
  float s = v.x + v.y + v.z + v.w;
  s = wave_reduce_sum(s);
  float mu = s * (1.f / 256.f);
  float dx = v.x - mu, dy = v.y - mu, dz = v.z - mu, dw = v.w - mu;
  float q = dx * dx + dy * dy + dz * dz + dw * dw;
  q = wave_reduce_sum(q);
  float rs = rsqrtf(q * (1.f / 256.f) + 1e-5f);
  float4 gv = reinterpret_cast<const float4*>(g)[lane];
  float4 bv = reinterpret_cast<const float4*>(bta)[lane];
  union { _Float16 h[4]; uint2 u; } pk;
  if (valid) {
    pk.h[0] = (_Float16)(dx * rs * gv.x + bv.x);
    pk.h[1] = (_Float16)(dy * rs * gv.y + bv.y);
    pk.h[2] = (_Float16)(dz * rs * gv.z + bv.z);
    pk.h[3] = (_Float16)(dw * rs * gv.w + bv.w);
  } else {
    pk.h[0] = pk.h[1] = pk.h[2] = pk.h[3] = (_Float16)0.f;
  }
  *reinterpret_cast<uint2*>(xw + (size_t)lrow * 256 + lane * 4) = pk.u;
}

// ---------------- plain LN2 (rows x 256, fp32 in -> f16 out) ------------------
__global__ __launch_bounds__(256) void ln2_kernel(
    const float* __restrict__ xin, const float* __restrict__ g,
    const float* __restrict__ bta, _Float16* __restrict__ y)
{
  int row = blockIdx.x * 4 + (threadIdx.x >> 6);
  int lane = threadIdx.x & 63;
  float4 v = reinterpret_cast<const float4*>(xin + (size_t)row * 256)[lane];
  float s = v.x + v.y + v.z + v.w;
  s = wave_reduce_sum(s);
  float mu = s * (1.f / 256.f);
  float dx = v.x - mu, dy = v.y - mu, dz = v.z - mu, dw = v.w - mu;
  float q = dx * dx + dy * dy + dz * dz + dw * dw;
  q = wave_reduce_sum(q);
  float rs = rsqrtf(q * (1.f / 256.f) + 1e-5f);
  float4 gv = reinterpret_cast<const float4*>(g)[lane];
  float4 bv = reinterpret_cast<const float4*>(bta)[lane];
  union { _Float16 h[4]; uint2 u; } pk;
  pk.h[0] = (_Float16)(dx * rs * gv.x + bv.x);
  pk.h[1] = (_Float16)(dy * rs * gv.y + bv.y);
  pk.h[2] = (_Float16)(dz * rs * gv.z + bv.z);
  pk.h[3] = (_Float16)(dw * rs * gv.w + bv.w);
  *reinterpret_cast<uint2*>(y + (size_t)row * 256 + lane * 4) = pk.u;
}

// --------------------------- MFMA f16 GEMM (Bt input) -------------------------
// C[M,N] = A[M,K] * Bt[N,K]^T + bias, 64x64 tile, 4 waves, 2x2 16x16x32 frags.
// mode 0: qkv  (scale cols<256 by 1/sqrt(32), f16 out)
// mode 1: proj (scatter reverse-window + residual add, fp32 out, skip pad rows;
//               gm+row0 gives the global attention row for the scatter)
// mode 2: fc1  (exact gelu, f16 out)
// mode 3: fc2  (in-place residual add on fp32 out)
__global__ __launch_bounds__(256) void gemm_kernel(
    const _Float16* __restrict__ A, const _Float16* __restrict__ Bt,
    const float* __restrict__ bias, const float* __restrict__ resid,
    void* __restrict__ out, int M, int N, int K, int mode, int row0)
{
  __shared__ __align__(16) _Float16 As[64][40];
  __shared__ __align__(16) _Float16 Bs[64][40];
  const int tid = threadIdx.x;
  const int m0 = blockIdx.x * 64, n0 = blockIdx.y * 64;
  const int wave = tid >> 6, lane = tid & 63;
  const int wm = (wave >> 1) * 32, wn = (wave & 1) * 32;
  const int quad = lane >> 4, l16 = lane & 15;
  const int srow = tid >> 2, scol = (tid & 3) * 8;

  f32x4 acc[2][2];
#pragma unroll
  for (int i = 0; i < 2; i++)
#pragma unroll
    for (int j = 0; j < 2; j++) acc[i][j] = (f32x4)0.f;

  for (int k0 = 0; k0 < K; k0 += 32) {
    uint4 av = make_uint4(0u, 0u, 0u, 0u);
    int gm = m0 + srow;
    if (gm < M) av = *reinterpret_cast<const uint4*>(A + (size_t)gm * K + k0 + scol);
    uint4 bv2 = *reinterpret_cast<const uint4*>(Bt + (size_t)(n0 + srow) * K + k0 + scol);
    *reinterpret_cast<uint4*>(&As[srow][scol]) = av;
    *reinterpret_cast<uint4*>(&Bs[srow][scol]) = bv2;
    __syncthreads();
    half8 a0 = *reinterpret_cast<const half8*>(&As[wm + l16][quad * 8]);
    half8 a1 = *reinterpret_cast<const half8*>(&As[wm + 16 + l16][quad * 8]);
    half8 b0 = *reinterpret_cast<const half8*>(&Bs[wn + l16][quad * 8]);
    half8 b1 = *reinterpret_cast<const half8*>(&Bs[wn + 16 + l16][quad * 8]);
    acc[0][0] = __builtin_amdgcn_mfma_f32_16x16x32_f16(a0, b0, acc[0][0], 0, 0, 0);
    acc[0][1] = __builtin_amdgcn_mfma_f32_16x16x32_f16(a0, b1, acc[0][1], 0, 0, 0);
    acc[1][0] = __builtin_amdgcn_mfma_f32_16x16x32_f16(a1, b0, acc[1][0], 0, 0, 0);
    acc[1][1] = __builtin_amdgcn_mfma_f32_16x16x32_f16(a1, b1, acc[1][1], 0, 0, 0);
    __syncthreads();
  }

#pragma unroll
  for (int i = 0; i < 2; i++) {
#pragma unroll
    for (int j = 0; j < 2; j++) {
      int gn = n0 + wn + j * 16 + l16;
      float bv = bias[gn];
#pragma unroll
      for (int r = 0; r < 4; r++) {
        int gm = m0 + wm + i * 16 + quad * 4 + r;
        if (gm >= M) continue;
        float v = acc[i][j][r] + bv;
        if (mode == 0) {
          if (gn < 256) v *= 0.17677669529663687f;   // 1/sqrt(32) on q
          reinterpret_cast<_Float16*>(out)[(size_t)gm * N + gn] = (_Float16)v;
        } else if (mode == 2) {
          v = 0.5f * v * (1.f + erff(v * 0.70710678118654752f));
          reinterpret_cast<_Float16*>(out)[(size_t)gm * N + gn] = (_Float16)v;
        } else if (mode == 3) {
          size_t o = (size_t)gm * N + gn;
          float* op = reinterpret_cast<float*>(out);
          op[o] = resid[o] + v;   // resid == out: in-place, 1 thread per elem
        } else {  // mode 1: reverse window + reverse shift + unpad + residual
          int gmg = gm + row0;
          int bw = gmg / 49, nn = gmg - bw * 49;
          int bb = bw / 81, win = bw - bb * 81;
          int wh = win / 9, wwn = win - wh * 9;
          int ii = nn / 7, jj = nn - ii * 7;
          int sh = wh * 7 + ii + 3; if (sh >= 63) sh -= 63;
          int sw = wwn * 7 + jj + 3; if (sw >= 63) sw -= 63;
          if (sh < 60 && sw < 60) {
            size_t o = ((size_t)bb * 3600 + sh * 60 + sw) * 256 + gn;
            reinterpret_cast<float*>(out)[o] = resid[o] + v;
          }
        }
      }
    }
  }
}

// ------------------------- windowed attention (vector) ------------------------
// one block (128 thr) per (window, head); qkv row-major (row, 768) f16.
// bw is chunk-local but chunks are whole batches, so win = bw % 81 is exact.
__global__ __launch_bounds__(128) void attn_kernel(
    const _Float16* __restrict__ qkv, const float* __restrict__ btab,
    _Float16* __restrict__ outp)
{
  __shared__ float qs[52][36], ks[52][36], vs[52][36];
  __shared__ float S[52][52];
  const int bwh = blockIdx.x;
  const int bw = bwh >> 3, head = bwh & 7;
  const int win = bw % 81;
  const int wh = win / 9, ww = win - wh * 9;
  const int tid = threadIdx.x;

  // zero pad rows 49..51 (cols 0..31) so patch loops need no guards
  for (int e = tid; e < 3 * 3 * 32; e += 128) {
    int a = e >> 5; int d = e & 31;
    int arr = a / 3, rr = 49 + a - arr * 3;
    float* p = arr == 0 ? &qs[rr][0] : (arr == 1 ? &ks[rr][0] : &vs[rr][0]);
    p[d] = 0.f;
  }
  const size_t base = (size_t)bw * 49 * 768 + head * 32;
  for (int e = tid; e < 49 * 32; e += 128) {
    int n = e >> 5, d = e & 31;
    size_t idx = base + (size_t)n * 768 + d;
    qs[n][d] = (float)qkv[idx];
    ks[n][d] = (float)qkv[idx + 256];
    vs[n][d] = (float)qkv[idx + 512];
  }
  __syncthreads();

  // scores: 13x13 patches of 4x4
  for (int p = tid; p < 169; p += 128) {
    int pn = p / 13, pm = p - pn * 13;
    int n0 = pn * 4, m0 = pm * 4;
    float accS[4][4];
#pragma unroll
    for (int a = 0; a < 4; a++)
#pragma unroll
      for (int b2 = 0; b2 < 4; b2++) accS[a][b2] = 0.f;
    for (int d = 0; d < 32; d += 4) {
      float4 qv[4], kv[4];
#pragma unroll
      for (int t = 0; t < 4; t++) {
        qv[t] = *reinterpret_cast<const float4*>(&qs[n0 + t][d]);
        kv[t] = *reinterpret_cast<const float4*>(&ks[m0 + t][d]);
      }
#pragma unroll
      for (int a = 0; a < 4; a++)
#pragma unroll
        for (int b2 = 0; b2 < 4; b2++)
          accS[a][b2] += qv[a].x * kv[b2].x + qv[a].y * kv[b2].y +
                         qv[a].z * kv[b2].z + qv[a].w * kv[b2].w;
    }
#pragma unroll
    for (int a = 0; a < 4; a++) {
      int n = n0 + a; int i1 = n / 7, j1 = n - i1 * 7;
      int ph = wh * 7 + i1, pw = ww * 7 + j1;
      int rh1 = ph < 56 ? 0 : (ph < 60 ? 1 : 2);
      int rw1 = pw < 56 ? 0 : (pw < 60 ? 1 : 2);
#pragma unroll
      for (int b2 = 0; b2 < 4; b2++) {
        int m = m0 + b2;
        float s;
        if (n < 49 && m < 49) {
          int i2 = m / 7, j2 = m - i2 * 7;
          s = accS[a][b2] + btab[((i1 - i2 + 6) * 13 + (j1 - j2 + 6)) * 8 + head];
          int ph2 = wh * 7 + i2, pw2 = ww * 7 + j2;
          int rh2 = ph2 < 56 ? 0 : (ph2 < 60 ? 1 : 2);
          int rw2 = pw2 < 56 ? 0 : (pw2 < 60 ? 1 : 2);
          if ((rh1 != rh2) || (rw1 != rw2)) s -= 100.f;
        } else {
          s = -1e30f;
        }
        S[n][m] = s;
      }
    }
  }
  __syncthreads();

  // row softmax (one thread per query row)
  if (tid < 49) {
    float mx = -1e30f;
    for (int m = 0; m < 49; m++) mx = fmaxf(mx, S[tid][m]);
    float sum = 0.f;
    for (int m = 0; m < 49; m++) {
      float e = __expf(S[tid][m] - mx);
      S[tid][m] = e; sum += e;
    }
    float inv = 1.f / sum;
    for (int m = 0; m < 49; m++) S[tid][m] *= inv;
  }
  __syncthreads();

  // P*V: 13 n-patches x 8 d-patches of 4x4
  for (int p = tid; p < 104; p += 128) {
    int pn = p >> 3, pd = p & 7;
    int n0 = pn * 4, d0 = pd * 4;
    float accO[4][4];
#pragma unroll
    for (int a = 0; a < 4; a++)
#pragma unroll
      for (int b2 = 0; b2 < 4; b2++) accO[a][b2] = 0.f;
    for (int m = 0; m < 49; m++) {
      float4 vv = *reinterpret_cast<const float4*>(&vs[m][d0]);
#pragma unroll
      for (int a = 0; a < 4; a++) {
        float sc = S[n0 + a][m];
        accO[a][0] += sc * vv.x; accO[a][1] += sc * vv.y;
        accO[a][2] += sc * vv.z; accO[a][3] += sc * vv.w;
      }
    }
#pragma unroll
    for (int a = 0; a < 4; a++) {
      int n = n0 + a;
      if (n < 49) {
        union { _Float16 h[4]; uint2 u; } pk;
#pragma unroll
        for (int c = 0; c < 4; c++) pk.h[c] = (_Float16)accO[a][c];
        *reinterpret_cast<uint2*>(
            &outp[((size_t)bw * 49 + n) * 256 + head * 32 + d0]) = pk.u;
      }
    }
  }
}

// --------------------------------- launcher -----------------------------------
extern "C" void kernel_launch(void* const* d_in, const int* in_sizes, int n_in,
                              void* d_out, int out_size, void* d_ws, size_t ws_size,
                              hipStream_t stream) {
  const float* x      = (const float*)d_in[0];
  const float* g1     = (const float*)d_in[1];
  const float* b1     = (const float*)d_in[2];
  const float* w_qkv  = (const float*)d_in[3];
  const float* b_qkv  = (const float*)d_in[4];
  const float* rbt    = (const float*)d_in[5];
  const float* w_proj = (const float*)d_in[6];
  const float* b_proj = (const float*)d_in[7];
  const float* g2     = (const float*)d_in[8];
  const float* b2     = (const float*)d_in[9];
  const float* w_fc1  = (const float*)d_in[10];
  const float* b_fc1  = (const float*)d_in[11];
  const float* w_fc2  = (const float*)d_in[12];
  const float* b_fc2  = (const float*)d_in[13];
  float* outp = (float*)d_out;   // doubles as the x2 residual buffer

  // weights (persistent, 1.5 MB)
  char* ws = (char*)d_ws;
  _Float16* wqkvT  = (_Float16*)(ws + 0);          // 768*256*2  = 393216
  _Float16* wprojT = (_Float16*)(ws + 393216);     // 256*256*2  = 131072
  _Float16* wfc1T  = (_Float16*)(ws + 524288);     // 1024*256*2 = 524288
  _Float16* wfc2T  = (_Float16*)(ws + 1048576);    // 256*1024*2 = 524288
  const size_t WB = 1572864;

  // chunk size: largest cb (batches per chunk) whose scratch fits ws_size.
  // region1 (xw/attn_out/y): cb*3969*256*2 = cb*2032128
  // region2 (qkv/h):         cb*3600*1024*2 = cb*7372800 (>= qkv's cb*6096384)
  const int cand[8] = {24, 12, 8, 6, 4, 3, 2, 1};
  int cb = 1;
  for (int ci = 0; ci < 8; ci++) {
    size_t need = WB + (size_t)cand[ci] * (2032128u + 7372800u);
    if (ws_size >= need) { cb = cand[ci]; break; }
  }
  const int nch = 24 / cb;

  _Float16* r1 = (_Float16*)(ws + WB);                               // xw / attn_out / y
  _Float16* r2 = (_Float16*)(ws + WB + (size_t)cb * 2032128u);       // qkv / h

  prep_weights<<<3072, 256, 0, stream>>>(w_qkv, w_proj, w_fc1, w_fc2,
                                         wqkvT, wprojT, wfc1T, wfc2T);

  for (int c = 0; c < nch; c++) {
    const int b0 = c * cb;
    const int rows_att = cb * 81 * 49;      // 3969*cb
    const int row0_att = b0 * 81 * 49;
    const int rows_mlp = cb * 3600;
    const int row0_mlp = b0 * 3600;

    // LN1 + shift + pad + window partition -> r1 (f16)
    ln1_window_kernel<<<(rows_att + 3) / 4, 256, 0, stream>>>(
        x, g1, b1, r1, row0_att, rows_att);
    // QKV GEMM -> r2 (f16), q pre-scaled
    {
      dim3 g((rows_att + 63) / 64, 12);
      gemm_kernel<<<g, 256, 0, stream>>>(r1, wqkvT, b_qkv, nullptr, r2,
                                         rows_att, 768, 256, 0, 0);
    }
    // windowed attention -> r1 (f16) (r1's xw is dead)
    attn_kernel<<<cb * 81 * 8, 128, 0, stream>>>(r2, rbt, r1);
    // proj GEMM + reverse-window scatter + residual -> d_out (fp32)
    {
      dim3 g((rows_att + 63) / 64, 4);
      gemm_kernel<<<g, 256, 0, stream>>>(r1, wprojT, b_proj, x, outp,
                                         rows_att, 256, 256, 1, row0_att);
    }
    // LN2 over this chunk's rows of d_out -> r1 (f16)
    ln2_kernel<<<rows_mlp / 4, 256, 0, stream>>>(
        outp + (size_t)row0_mlp * 256, g2, b2, r1);
    // FC1 + GELU -> r2 (f16)
    {
      dim3 g((rows_mlp + 63) / 64, 16);
      gemm_kernel<<<g, 256, 0, stream>>>(r1, wfc1T, b_fc1, nullptr, r2,
                                         rows_mlp, 1024, 256, 2, 0);
    }
    // FC2 + in-place residual on d_out (fp32)
    {
      dim3 g((rows_mlp + 63) / 64, 4);
      float* od = outp + (size_t)row0_mlp * 256;
      gemm_kernel<<<g, 256, 0, stream>>>(r2, wfc2T, b_fc2, od, od,
                                         rows_mlp, 256, 1024, 3, 0);
    }
  }
}

// Round 3
// 830.608 us; speedup vs baseline: 1.4697x; 1.4697x over previous
//
#include <hip/hip_runtime.h>
#include <hip/hip_bf16.h>
#include <math.h>

// ---- static problem config ----
// B=24, H=W=60, DIM=256, NH=8, HD=32, WS=7, SS=3, N=49, HP=WP=63, NW=81
// rows_att = 24*81*49 = 95256 ; rows_mlp = 24*3600 = 86400

typedef _Float16 half8 __attribute__((ext_vector_type(8)));
typedef _Float16 half4_t __attribute__((ext_vector_type(4)));
typedef float f32x4 __attribute__((ext_vector_type(4)));

__device__ __forceinline__ float wave_reduce_sum(float v) {
  v += __shfl_xor(v, 1);
  v += __shfl_xor(v, 2);
  v += __shfl_xor(v, 4);
  v += __shfl_xor(v, 8);
  v += __shfl_xor(v, 16);
  v += __shfl_xor(v, 32);
  return v;
}

// ---------------- weight transpose + f16 convert (Bt layout: N x K) -----------
__global__ __launch_bounds__(256) void prep_weights(
    const float* __restrict__ wqkv, const float* __restrict__ wproj,
    const float* __restrict__ wfc1, const float* __restrict__ wfc2,
    _Float16* __restrict__ oqkv, _Float16* __restrict__ oproj,
    _Float16* __restrict__ ofc1, _Float16* __restrict__ ofc2)
{
  int idx = blockIdx.x * 256 + threadIdx.x;
  if (idx < 196608) {                       // w_qkv: 256x768 -> 768x256
    int n = idx / 256, k = idx % 256;
    oqkv[idx] = (_Float16)wqkv[k * 768 + n];
  } else if (idx < 262144) {                // w_proj: 256x256 -> 256x256
    int i = idx - 196608; int n = i / 256, k = i % 256;
    oproj[i] = (_Float16)wproj[k * 256 + n];
  } else if (idx < 524288) {                // w_fc1: 256x1024 -> 1024x256
    int i = idx - 262144; int n = i / 256, k = i % 256;
    ofc1[i] = (_Float16)wfc1[k * 1024 + n];
  } else {                                  // w_fc2: 1024x256 -> 256x1024
    int i = idx - 524288; int n = i / 1024, k = i % 1024;
    ofc2[i] = (_Float16)wfc2[k * 256 + n];
  }
}

// ------- combined rel-bias + shift-mask table: CB[class][head][64][64] f16 ----
// class c: bit1 = (wh==8), bit0 = (ww==8). Pad rows/cols get -60000 (softmax 0).
__global__ __launch_bounds__(256) void prep_cb(
    const float* __restrict__ rbt, _Float16* __restrict__ cbt)
{
  int idx = blockIdx.x * 256 + threadIdx.x;   // 4*8*64*64 = 131072
  int m = idx & 63, n = (idx >> 6) & 63;
  int hc = idx >> 12; int h = hc & 7, c = hc >> 3;
  float v;
  if (n < 49 && m < 49) {
    int i1 = n / 7, j1 = n % 7, i2 = m / 7, j2 = m % 7;
    float bias = rbt[((i1 - i2 + 6) * 13 + (j1 - j2 + 6)) * 8 + h];
    int rh1 = (c & 2) ? (i1 < 4 ? 1 : 2) : 0;
    int rh2 = (c & 2) ? (i2 < 4 ? 1 : 2) : 0;
    int rw1 = (c & 1) ? (j1 < 4 ? 1 : 2) : 0;
    int rw2 = (c & 1) ? (j2 < 4 ? 1 : 2) : 0;
    v = bias + (((rh1 != rh2) || (rw1 != rw2)) ? -100.f : 0.f);
  } else {
    v = -60000.f;
  }
  cbt[idx] = (_Float16)v;
}

// --------- LN1 fused with pad + cyclic shift(-3,-3) + window partition --------
__global__ __launch_bounds__(256) void ln1_window_kernel(
    const float* __restrict__ x, const float* __restrict__ g,
    const float* __restrict__ bta, _Float16* __restrict__ xw,
    int row0, int rows_c)
{
  int lrow = blockIdx.x * 4 + (threadIdx.x >> 6);
  if (lrow >= rows_c) return;               // whole wave exits together
  int row = row0 + lrow;
  int lane = threadIdx.x & 63;
  int bw = row / 49, n = row - bw * 49;
  int b = bw / 81, win = bw - b * 81;
  int wh = win / 9, ww = win - wh * 9;
  int i = n / 7, j = n - i * 7;
  int sh = wh * 7 + i + 3; if (sh >= 63) sh -= 63;
  int sw = ww * 7 + j + 3; if (sw >= 63) sw -= 63;
  bool valid = (sh < 60) && (sw < 60);
  float4 v = make_float4(0.f, 0.f, 0.f, 0.f);
  if (valid)
    v = reinterpret_cast<const float4*>(x + ((size_t)b * 3600 + sh * 60 + sw) * 256)[lane];
  float s = v.x + v.y + v.z + v.w;
  s = wave_reduce_sum(s);
  float mu = s * (1.f / 256.f);
  float dx = v.x - mu, dy = v.y - mu, dz = v.z - mu, dw = v.w - mu;
  float q = dx * dx + dy * dy + dz * dz + dw * dw;
  q = wave_reduce_sum(q);
  float rs = rsqrtf(q * (1.f / 256.f) + 1e-5f);
  float4 gv = reinterpret_cast<const float4*>(g)[lane];
  float4 bv = reinterpret_cast<const float4*>(bta)[lane];
  union { _Float16 h[4]; uint2 u; } pk;
  if (valid) {
    pk.h[0] = (_Float16)(dx * rs * gv.x + bv.x);
    pk.h[1] = (_Float16)(dy * rs * gv.y + bv.y);
    pk.h[2] = (_Float16)(dz * rs * gv.z + bv.z);
    pk.h[3] = (_Float16)(dw * rs * gv.w + bv.w);
  } else {
    pk.h[0] = pk.h[1] = pk.h[2] = pk.h[3] = (_Float16)0.f;
  }
  *reinterpret_cast<uint2*>(xw + (size_t)lrow * 256 + lane * 4) = pk.u;
}

// ---------------- plain LN2 (rows x 256, fp32 in -> f16 out) ------------------
__global__ __launch_bounds__(256) void ln2_kernel(
    const float* __restrict__ xin, const float* __restrict__ g,
    const float* __restrict__ bta, _Float16* __restrict__ y)
{
  int row = blockIdx.x * 4 + (threadIdx.x >> 6);
  int lane = threadIdx.x & 63;
  float4 v = reinterpret_cast<const float4*>(xin + (size_t)row * 256)[lane];
  float s = v.x + v.y + v.z + v.w;
  s = wave_reduce_sum(s);
  float mu = s * (1.f / 256.f);
  float dx = v.x - mu, dy = v.y - mu, dz = v.z - mu, dw = v.w - mu;
  float q = dx * dx + dy * dy + dz * dz + dw * dw;
  q = wave_reduce_sum(q);
  float rs = rsqrtf(q * (1.f / 256.f) + 1e-5f);
  float4 gv = reinterpret_cast<const float4*>(g)[lane];
  float4 bv = reinterpret_cast<const float4*>(bta)[lane];
  union { _Float16 h[4]; uint2 u; } pk;
  pk.h[0] = (_Float16)(dx * rs * gv.x + bv.x);
  pk.h[1] = (_Float16)(dy * rs * gv.y + bv.y);
  pk.h[2] = (_Float16)(dz * rs * gv.z + bv.z);
  pk.h[3] = (_Float16)(dw * rs * gv.w + bv.w);
  *reinterpret_cast<uint2*>(y + (size_t)row * 256 + lane * 4) = pk.u;
}

// --------------------------- MFMA f16 GEMM (Bt input) -------------------------
// C[M,N] = A[M,K] * Bt[N,K]^T + bias, 64x64 tile, 4 waves, 2x2 16x16x32 frags.
__global__ __launch_bounds__(256) void gemm_kernel(
    const _Float16* __restrict__ A, const _Float16* __restrict__ Bt,
    const float* __restrict__ bias, const float* __restrict__ resid,
    void* __restrict__ out, int M, int N, int K, int mode, int row0)
{
  __shared__ __align__(16) _Float16 As[64][40];
  __shared__ __align__(16) _Float16 Bs[64][40];
  const int tid = threadIdx.x;
  const int m0 = blockIdx.x * 64, n0 = blockIdx.y * 64;
  const int wave = tid >> 6, lane = tid & 63;
  const int wm = (wave >> 1) * 32, wn = (wave & 1) * 32;
  const int quad = lane >> 4, l16 = lane & 15;
  const int srow = tid >> 2, scol = (tid & 3) * 8;

  f32x4 acc[2][2];
#pragma unroll
  for (int i = 0; i < 2; i++)
#pragma unroll
    for (int j = 0; j < 2; j++) acc[i][j] = (f32x4)0.f;

  for (int k0 = 0; k0 < K; k0 += 32) {
    uint4 av = make_uint4(0u, 0u, 0u, 0u);
    int gm = m0 + srow;
    if (gm < M) av = *reinterpret_cast<const uint4*>(A + (size_t)gm * K + k0 + scol);
    uint4 bv2 = *reinterpret_cast<const uint4*>(Bt + (size_t)(n0 + srow) * K + k0 + scol);
    *reinterpret_cast<uint4*>(&As[srow][scol]) = av;
    *reinterpret_cast<uint4*>(&Bs[srow][scol]) = bv2;
    __syncthreads();
    half8 a0 = *reinterpret_cast<const half8*>(&As[wm + l16][quad * 8]);
    half8 a1 = *reinterpret_cast<const half8*>(&As[wm + 16 + l16][quad * 8]);
    half8 b0 = *reinterpret_cast<const half8*>(&Bs[wn + l16][quad * 8]);
    half8 b1 = *reinterpret_cast<const half8*>(&Bs[wn + 16 + l16][quad * 8]);
    acc[0][0] = __builtin_amdgcn_mfma_f32_16x16x32_f16(a0, b0, acc[0][0], 0, 0, 0);
    acc[0][1] = __builtin_amdgcn_mfma_f32_16x16x32_f16(a0, b1, acc[0][1], 0, 0, 0);
    acc[1][0] = __builtin_amdgcn_mfma_f32_16x16x32_f16(a1, b0, acc[1][0], 0, 0, 0);
    acc[1][1] = __builtin_amdgcn_mfma_f32_16x16x32_f16(a1, b1, acc[1][1], 0, 0, 0);
    __syncthreads();
  }

#pragma unroll
  for (int i = 0; i < 2; i++) {
#pragma unroll
    for (int j = 0; j < 2; j++) {
      int gn = n0 + wn + j * 16 + l16;
      float bv = bias[gn];
#pragma unroll
      for (int r = 0; r < 4; r++) {
        int gm = m0 + wm + i * 16 + quad * 4 + r;
        if (gm >= M) continue;
        float v = acc[i][j][r] + bv;
        if (mode == 0) {
          if (gn < 256) v *= 0.17677669529663687f;   // 1/sqrt(32) on q
          reinterpret_cast<_Float16*>(out)[(size_t)gm * N + gn] = (_Float16)v;
        } else if (mode == 2) {
          v = 0.5f * v * (1.f + erff(v * 0.70710678118654752f));
          reinterpret_cast<_Float16*>(out)[(size_t)gm * N + gn] = (_Float16)v;
        } else if (mode == 3) {
          size_t o = (size_t)gm * N + gn;
          float* op = reinterpret_cast<float*>(out);
          op[o] = resid[o] + v;   // resid == out: in-place, 1 thread per elem
        } else {  // mode 1: reverse window + reverse shift + unpad + residual
          int gmg = gm + row0;
          int bw = gmg / 49, nn = gmg - bw * 49;
          int bb = bw / 81, win = bw - bb * 81;
          int wh = win / 9, wwn = win - wh * 9;
          int ii = nn / 7, jj = nn - ii * 7;
          int sh = wh * 7 + ii + 3; if (sh >= 63) sh -= 63;
          int sw = wwn * 7 + jj + 3; if (sw >= 63) sw -= 63;
          if (sh < 60 && sw < 60) {
            size_t o = ((size_t)bb * 3600 + sh * 60 + sw) * 256 + gn;
            reinterpret_cast<float*>(out)[o] = resid[o] + v;
          }
        }
      }
    }
  }
}

// ------------------------ MFMA windowed attention -----------------------------
// One wave (64 thr) per (window, head). S^T = K*Q^T (16 mfma, K-dim=32 exact),
// register softmax over m, P->LDS (f16, packed b64), O^T = V^T*P^T (16 mfma).
// Q is pre-scaled by 1/sqrt(32) in the QKV GEMM. CB table supplies bias+mask
// (-60000 on pad rows/cols -> P=0 there; pad Q/K frags are zero-masked).
__global__ __launch_bounds__(64) void attn_mfma(
    const _Float16* __restrict__ qkv, const _Float16* __restrict__ cbt,
    _Float16* __restrict__ outp)
{
  __shared__ __align__(16) _Float16 VT[32][72];   // V^T[d][m], m 49..63 zeroed
  __shared__ __align__(16) _Float16 Ps[64][72];   // P[n][m]
  const int bwh = blockIdx.x;
  const int bw = bwh >> 3, h = bwh & 7;
  const int win = bw % 81;
  const int wh = win / 9, ww = win - wh * 9;
  const int cls = ((wh == 8) ? 2 : 0) | ((ww == 8) ? 1 : 0);
  const int lane = threadIdx.x;
  const int quad = lane >> 4, l16 = lane & 15;

  // ---- stage V^T into LDS (coalesced read, scalar transposed writes) ----
  for (int e = lane; e < 480; e += 64) {          // zero pad cols m=49..63
    int d = e / 15, m = 49 + e % 15;
    VT[d][m] = (_Float16)0.f;
  }
  const size_t vbase = (size_t)bw * 49 * 768 + 512 + h * 32;
  for (int e = lane; e < 1568; e += 64) {
    int m = e >> 5, d = e & 31;
    VT[d][m] = qkv[vbase + (size_t)m * 768 + d];
  }

  // ---- Q/K fragments direct from global (clamped rows, zero-masked pad) ----
  const _Float16* qb = qkv + (size_t)bw * 49 * 768 + h * 32 + quad * 8;
  half8 kf[4], qf[4];
  const half8 hz = (half8)(_Float16)0.f;
#pragma unroll
  for (int t = 0; t < 4; t++) {
    int row = t * 16 + l16;
    int rc = row < 49 ? row : 48;
    half8 kv = *reinterpret_cast<const half8*>(qb + 256 + (size_t)rc * 768);
    half8 qv = *reinterpret_cast<const half8*>(qb + (size_t)rc * 768);
    kf[t] = row < 49 ? kv : hz;
    qf[t] = row < 49 ? qv : hz;
  }

  // ---- S^T = K * Q^T : tiles (mt, nt), one K-step (d=32) each ----
  f32x4 S[4][4];
#pragma unroll
  for (int mt = 0; mt < 4; mt++)
#pragma unroll
    for (int nt = 0; nt < 4; nt++) S[mt][nt] = (f32x4)0.f;
#pragma unroll
  for (int mt = 0; mt < 4; mt++)
#pragma unroll
    for (int nt = 0; nt < 4; nt++)
      S[mt][nt] = __builtin_amdgcn_mfma_f32_16x16x32_f16(kf[mt], qf[nt], S[mt][nt], 0, 0, 0);

  // ---- add bias+mask: CB[n][m], C-layout elem (m = mt*16+quad*4+r, n = nt*16+l16)
  const _Float16* cbp = cbt + (((size_t)cls * 8 + h) << 12);
#pragma unroll
  for (int nt = 0; nt < 4; nt++) {
    int n = nt * 16 + l16;
#pragma unroll
    for (int mt = 0; mt < 4; mt++) {
      half4_t cb4 = *reinterpret_cast<const half4_t*>(cbp + n * 64 + mt * 16 + quad * 4);
#pragma unroll
      for (int r = 0; r < 4; r++) S[mt][nt][r] += (float)cb4[r];
    }
  }

  // ---- softmax over m (in-register + cross-quad shuffles), fold 1/sum into P
  float inv[4];
#pragma unroll
  for (int nt = 0; nt < 4; nt++) {
    float mx = -3.0e38f;
#pragma unroll
    for (int mt = 0; mt < 4; mt++)
#pragma unroll
      for (int r = 0; r < 4; r++) mx = fmaxf(mx, S[mt][nt][r]);
    mx = fmaxf(mx, __shfl_xor(mx, 16));
    mx = fmaxf(mx, __shfl_xor(mx, 32));
    float sm = 0.f;
#pragma unroll
    for (int mt = 0; mt < 4; mt++)
#pragma unroll
      for (int r = 0; r < 4; r++) {
        float e = __expf(S[mt][nt][r] - mx);
        S[mt][nt][r] = e;
        sm += e;
      }
    sm += __shfl_xor(sm, 16);
    sm += __shfl_xor(sm, 32);
    inv[nt] = 1.f / sm;
  }

  // ---- P -> LDS as [n][m] f16, packed 4-wide (b64) ----
#pragma unroll
  for (int nt = 0; nt < 4; nt++) {
#pragma unroll
    for (int mt = 0; mt < 4; mt++) {
      half4_t p;
#pragma unroll
      for (int r = 0; r < 4; r++) p[r] = (_Float16)(S[mt][nt][r] * inv[nt]);
      *reinterpret_cast<half4_t*>(&Ps[nt * 16 + l16][mt * 16 + quad * 4]) = p;
    }
  }
  __syncthreads();   // single wave: just drains LDS; makes VT+Ps visible

  // ---- O^T = V^T * P^T : tiles (dt, nt), K-dim m = 64 -> 2 steps ----
  f32x4 O[2][4];
#pragma unroll
  for (int dt = 0; dt < 2; dt++)
#pragma unroll
    for (int nt = 0; nt < 4; nt++) O[dt][nt] = (f32x4)0.f;
#pragma unroll
  for (int ks = 0; ks < 2; ks++) {
    half8 va[2], pb[4];
#pragma unroll
    for (int dt = 0; dt < 2; dt++)
      va[dt] = *reinterpret_cast<const half8*>(&VT[dt * 16 + l16][ks * 32 + quad * 8]);
#pragma unroll
    for (int nt = 0; nt < 4; nt++)
      pb[nt] = *reinterpret_cast<const half8*>(&Ps[nt * 16 + l16][ks * 32 + quad * 8]);
#pragma unroll
    for (int dt = 0; dt < 2; dt++)
#pragma unroll
      for (int nt = 0; nt < 4; nt++)
        O[dt][nt] = __builtin_amdgcn_mfma_f32_16x16x32_f16(va[dt], pb[nt], O[dt][nt], 0, 0, 0);
  }

  // ---- write O: C-layout elem (d = dt*16+quad*4+r, n = nt*16+l16) ----
#pragma unroll
  for (int nt = 0; nt < 4; nt++) {
    int n = nt * 16 + l16;
    if (n < 49) {
#pragma unroll
      for (int dt = 0; dt < 2; dt++) {
        half4_t o4;
#pragma unroll
        for (int r = 0; r < 4; r++) o4[r] = (_Float16)O[dt][nt][r];
        *reinterpret_cast<half4_t*>(
            outp + ((size_t)bw * 49 + n) * 256 + h * 32 + dt * 16 + quad * 4) = o4;
      }
    }
  }
}

// --------------------------------- launcher -----------------------------------
extern "C" void kernel_launch(void* const* d_in, const int* in_sizes, int n_in,
                              void* d_out, int out_size, void* d_ws, size_t ws_size,
                              hipStream_t stream) {
  const float* x      = (const float*)d_in[0];
  const float* g1     = (const float*)d_in[1];
  const float* b1     = (const float*)d_in[2];
  const float* w_qkv  = (const float*)d_in[3];
  const float* b_qkv  = (const float*)d_in[4];
  const float* rbt    = (const float*)d_in[5];
  const float* w_proj = (const float*)d_in[6];
  const float* b_proj = (const float*)d_in[7];
  const float* g2     = (const float*)d_in[8];
  const float* b2     = (const float*)d_in[9];
  const float* w_fc1  = (const float*)d_in[10];
  const float* b_fc1  = (const float*)d_in[11];
  const float* w_fc2  = (const float*)d_in[12];
  const float* b_fc2  = (const float*)d_in[13];
  float* outp = (float*)d_out;   // doubles as the x2 residual buffer

  // weights (persistent): 1.5 MB transposed f16 + 256 KB CB table
  char* ws = (char*)d_ws;
  _Float16* wqkvT  = (_Float16*)(ws + 0);          // 768*256*2  = 393216
  _Float16* wprojT = (_Float16*)(ws + 393216);     // 256*256*2  = 131072
  _Float16* wfc1T  = (_Float16*)(ws + 524288);     // 1024*256*2 = 524288
  _Float16* wfc2T  = (_Float16*)(ws + 1048576);    // 256*1024*2 = 524288
  _Float16* cbt    = (_Float16*)(ws + 1572864);    // 4*8*64*64*2 = 262144
  const size_t WB = 1835008;

  // chunk size: largest cb (batches per chunk) whose scratch fits ws_size.
  // region1 (xw/attn_out/y): cb*3969*256*2 = cb*2032128
  // region2 (qkv/h):         cb*3600*1024*2 = cb*7372800 (>= qkv's cb*6096384)
  const int cand[8] = {24, 12, 8, 6, 4, 3, 2, 1};
  int cb = 1;
  for (int ci = 0; ci < 8; ci++) {
    size_t need = WB + (size_t)cand[ci] * (2032128u + 7372800u);
    if (ws_size >= need) { cb = cand[ci]; break; }
  }
  const int nch = 24 / cb;

  _Float16* r1 = (_Float16*)(ws + WB);                               // xw / attn_out / y
  _Float16* r2 = (_Float16*)(ws + WB + (size_t)cb * 2032128u);       // qkv / h

  prep_weights<<<3072, 256, 0, stream>>>(w_qkv, w_proj, w_fc1, w_fc2,
                                         wqkvT, wprojT, wfc1T, wfc2T);
  prep_cb<<<512, 256, 0, stream>>>(rbt, cbt);

  for (int c = 0; c < nch; c++) {
    const int b0 = c * cb;
    const int rows_att = cb * 81 * 49;      // 3969*cb
    const int row0_att = b0 * 81 * 49;
    const int rows_mlp = cb * 3600;
    const int row0_mlp = b0 * 3600;

    // LN1 + shift + pad + window partition -> r1 (f16)
    ln1_window_kernel<<<(rows_att + 3) / 4, 256, 0, stream>>>(
        x, g1, b1, r1, row0_att, rows_att);
    // QKV GEMM -> r2 (f16), q pre-scaled
    {
      dim3 g((rows_att + 63) / 64, 12);
      gemm_kernel<<<g, 256, 0, stream>>>(r1, wqkvT, b_qkv, nullptr, r2,
                                         rows_att, 768, 256, 0, 0);
    }
    // MFMA windowed attention -> r1 (f16) (r1's xw is dead)
    attn_mfma<<<cb * 81 * 8, 64, 0, stream>>>(r2, cbt, r1);
    // proj GEMM + reverse-window scatter + residual -> d_out (fp32)
    {
      dim3 g((rows_att + 63) / 64, 4);
      gemm_kernel<<<g, 256, 0, stream>>>(r1, wprojT, b_proj, x, outp,
                                         rows_att, 256, 256, 1, row0_att);
    }
    // LN2 over this chunk's rows of d_out -> r1 (f16)
    ln2_kernel<<<rows_mlp / 4, 256, 0, stream>>>(
        outp + (size_t)row0_mlp * 256, g2, b2, r1);
    // FC1 + GELU -> r2 (f16)
    {
      dim3 g((rows_mlp + 63) / 64, 16);
      gemm_kernel<<<g, 256, 0, stream>>>(r1, wfc1T, b_fc1, nullptr, r2,
                                         rows_mlp, 1024, 256, 2, 0);
    }
    // FC2 + in-place residual on d_out (fp32)
    {
      dim3 g((rows_mlp + 63) / 64, 4);
      float* od = outp + (size_t)row0_mlp * 256;
      gemm_kernel<<<g, 256, 0, stream>>>(r2, wfc2T, b_fc2, od, od,
                                         rows_mlp, 256, 1024, 3, 0);
    }
  }
}